// Round 9
// baseline (471.246 us; speedup 1.0000x reference)
//
#include <hip/hip_runtime.h>
#include <math.h>

#define A_W 0.955f
#define B_W 1.3693f
#define INF_W 1e6f
#define HDIM 512
#define WDIM 512
#define NPIX (HDIM*WDIM)
#define NSAMP 16
#define NTOT_F 4194304.0f
#define TST 16      // strip height
#define NSTRIP 32   // strips per sample

// ws layout (bytes):
//  [0,384):        float acc[96]: [s]=S1 [16+s]=S2 [32+s]=inter [48+s]=totp [64+s]=mx [80+s]=focal
//  [512,768):      int flags[64]: [0..15]=has_b [16..31]=has_fg
//  [1024,5120):    int blkflags[1024]
//  [8192,20480):   float stripacc[6][512]
//  [1MB,2MB):      float Llast[16][32][512]
//  [2MB,3MB):      float bounds[16][32][512]
//  [3MB,19MB):     float dB[16][512][512]   (pass-1 result)
#define OFF_SACC   8192
#define OFF_LLAST  (1u<<20)
#define OFF_BOUNDS (2u<<20)
#define OFF_DB     (3u<<20)

// DPP move with INF fill (floats).
//   WAVE_SHR1 (0x138): lane i <- lane i-1 (== __shfl_up 1)
//   WAVE_SHL1 (0x130): lane i <- lane i+1 (== __shfl_down 1)
template<int CTRL, int RMASK>
__device__ __forceinline__ float dpp_mov_inf(float x) {
    return __int_as_float(__builtin_amdgcn_update_dpp(
        __float_as_int(INF_W), __float_as_int(x), CTRL, RMASK, 0xF, false));
}
// DPP move with 0 fill (ints; bound_ctrl=1 -> OOB lanes read 0).
template<int CTRL>
__device__ __forceinline__ int dpp_mov0_i(int x) {
    return __builtin_amdgcn_update_dpp(0, x, CTRL, 0xF, 0xF, true);
}

__device__ __forceinline__ float wave_prefix_min_incl(float t) {
    t = fminf(t, dpp_mov_inf<0x111,0xF>(t));   // row_shr:1
    t = fminf(t, dpp_mov_inf<0x112,0xF>(t));   // row_shr:2
    t = fminf(t, dpp_mov_inf<0x114,0xF>(t));   // row_shr:4
    t = fminf(t, dpp_mov_inf<0x118,0xF>(t));   // row_shr:8
    t = fminf(t, dpp_mov_inf<0x142,0xA>(t));   // row_bcast:15 -> rows 1,3
    t = fminf(t, dpp_mov_inf<0x143,0xC>(t));   // row_bcast:31 -> rows 2,3
    return t;
}

// v[j] <- min_{k<=j} (v[k] + A*(j-k))
__device__ __forceinline__ void cummin_row(const float* jc, float* v) {
    float g[8];
#pragma unroll
    for (int i = 0; i < 8; ++i) g[i] = v[i] - jc[i];
    float c1[8];
    c1[0] = g[0];
#pragma unroll
    for (int i = 1; i < 8; ++i) c1[i] = fminf(g[i], g[i-1]);
    float c2[8];
    c2[0] = c1[0]; c2[1] = c1[1];
#pragma unroll
    for (int i = 2; i < 8; ++i) c2[i] = fminf(c1[i], c1[i-2]);
    float cj[8];
    cj[0] = c2[0]; cj[1] = c2[1]; cj[2] = c2[2]; cj[3] = c2[3];
#pragma unroll
    for (int i = 4; i < 8; ++i) cj[i] = fminf(c2[i], c2[i-4]);
    float t  = wave_prefix_min_incl(cj[7]);
    float ex = dpp_mov_inf<0x138,0xF>(t);
#pragma unroll
    for (int i = 0; i < 8; ++i) v[i] = jc[i] + fminf(cj[i], ex);
}

__device__ __forceinline__ void row_step(const float* jc, float* prev, const float* drow) {
    float lIn = dpp_mov_inf<0x138,0xF>(prev[7]);
    float rIn = dpp_mov_inf<0x130,0xF>(prev[0]);
    float m[8];
#pragma unroll
    for (int i = 0; i < 8; ++i) {
        float up = prev[i] + A_W;
        float ul = ((i == 0) ? lIn : prev[i-1]) + B_W;
        float ur = ((i == 7) ? rIn : prev[i+1]) + B_W;
        m[i] = fminf(fminf(drow[i], up), fminf(ul, ur));
    }
    cummin_row(jc, m);
#pragma unroll
    for (int i = 0; i < 8; ++i) prev[i] = m[i];
}

// 4 fused T3 steps (exact, INF outside grid).
__device__ __forceinline__ void t3x4(float* b) {
    float e[16];
#pragma unroll
    for (int k = 0; k < 4; ++k) e[k]    = dpp_mov_inf<0x138,0xF>(b[4+k]);
#pragma unroll
    for (int k = 0; k < 8; ++k) e[4+k]  = b[k];
#pragma unroll
    for (int k = 0; k < 4; ++k) e[12+k] = dpp_mov_inf<0x130,0xF>(b[k]);
    const float w0 = 4.f*A_W, w1 = 3.f*A_W + B_W, w2 = 2.f*A_W + 2.f*B_W;
    const float w3 = A_W + 3.f*B_W, w4 = 4.f*B_W;
#pragma unroll
    for (int i = 0; i < 8; ++i) {
        float m = e[i+4] + w0;
        m = fminf(m, fminf(e[i+3], e[i+5]) + w1);
        m = fminf(m, fminf(e[i+2], e[i+6]) + w2);
        m = fminf(m, fminf(e[i+1], e[i+7]) + w3);
        m = fminf(m, fminf(e[i+0], e[i+8]) + w4);
        b[i] = m;
    }
}

// ---- inline seed machinery --------------------------------------------------
struct RowBits { int efg; int ebg; int rawbg; };

__device__ __forceinline__ RowBits make_rowbits(uint4 a, uint4 b) {
    int fg = ((a.x!=0u)?1:0) | ((a.y!=0u)?2:0) | ((a.z!=0u)?4:0) | ((a.w!=0u)?8:0)
           | ((b.x!=0u)?16:0) | ((b.y!=0u)?32:0) | ((b.z!=0u)?64:0) | ((b.w!=0u)?128:0);
    int bg = (~fg) & 0xFF;
    int lf = dpp_mov0_i<0x138>(fg), rf = dpp_mov0_i<0x130>(fg);
    int lb = dpp_mov0_i<0x138>(bg), rb = dpp_mov0_i<0x130>(bg);
    RowBits r;
    r.efg = (fg | (fg<<1) | (fg>>1) | ((lf>>7)&1) | ((rf&1)<<7)) & 0xFF;
    r.ebg = (bg | (bg<<1) | (bg>>1) | ((lb>>7)&1) | ((rb&1)<<7)) & 0xFF;
    r.rawbg = bg;
    return r;
}

// ---- flags: has_fg / has_bg (has_b == has_fg && has_bg) ---------------------
__global__ __launch_bounds__(256) void flags1_kernel(const int* __restrict__ tg,
                                                     int* __restrict__ blkflags) {
    const int4* p = (const int4*)tg + (size_t)blockIdx.x * 4096 + threadIdx.x;
    int fgany = 0, bgany = 0;
#pragma unroll 4
    for (int i = 0; i < 16; ++i) {
        int4 v = p[i * 256];
        fgany |= (v.x | v.y | v.z | v.w);
        bgany |= (v.x == 0) | (v.y == 0) | (v.z == 0) | (v.w == 0);
    }
    int wf = __any(fgany != 0) ? 1 : 0;
    int wb = __any(bgany != 0) ? 2 : 0;
    if ((threadIdx.x & 63) == 0) blkflags[blockIdx.x * 4 + (threadIdx.x >> 6)] = wf | wb;
}

__global__ __launch_bounds__(64) void flags2_kernel(const int* __restrict__ blkflags,
                                                    int* __restrict__ flags) {
    const int s = blockIdx.x;
    const int lane = threadIdx.x;
    int v = blkflags[s * 64 + lane];
#pragma unroll
    for (int off = 32; off > 0; off >>= 1) v |= __shfl_xor(v, off);
    if (lane == 0) {
        int hfg = v & 1, hbg = (v >> 1) & 1;
        flags[s] = hfg & hbg;     // has_b
        flags[16 + s] = hfg;      // has_fg
    }
}

// Phase 1, pass 1: local strip scan with inline seeds; write last row only.
__global__ __launch_bounds__(64) void strip1a_kernel(const int* __restrict__ tg,
                                                     const int* __restrict__ flags,
                                                     float* __restrict__ Llast) {
    const int s = blockIdx.x >> 5, sig = blockIdx.x & 31;
    const int lane = threadIdx.x;
    const int c0 = lane * 8;
    const int* tgb = tg + (size_t)s * NPIX;
    const bool useb = flags[s] != 0;
    const int R0 = sig * TST;
    float jc[8];
#pragma unroll
    for (int i = 0; i < 8; ++i) jc[i] = A_W * (float)(c0 + i);

    auto loadrow = [&](int rr) -> RowBits {
        if (rr < 0 || rr >= HDIM) { RowBits z; z.efg = 0; z.ebg = 0; z.rawbg = 0; return z; }
        const uint4* p = (const uint4*)(tgb + (size_t)rr * WDIM + c0);
        return make_rowbits(p[0], p[1]);
    };

    RowBits rA = loadrow(R0 - 1);
    RowBits rB = loadrow(R0);
    float prev[8];
#pragma unroll
    for (int i = 0; i < 8; ++i) prev[i] = INF_W;

#pragma unroll
    for (int t = 0; t < TST; ++t) {
        RowBits rC = loadrow(R0 + t + 1);
        int smask = useb ? ((rA.efg | rB.efg | rC.efg) & (rA.ebg | rB.ebg | rC.ebg))
                         : rB.rawbg;
        float dr[8];
#pragma unroll
        for (int i = 0; i < 8; ++i) dr[i] = ((smask >> i) & 1) ? 0.f : INF_W;
        row_step(jc, prev, dr);
        rA = rB; rB = rC;
    }
    float* Lr = Llast + ((size_t)s * NSTRIP + sig) * WDIM + c0;
    *(float4*)Lr       = make_float4(prev[0], prev[1], prev[2], prev[3]);
    *(float4*)(Lr + 4) = make_float4(prev[4], prev[5], prev[6], prev[7]);
}

// Phase 2: exact sequential boundary propagation across strips.
__global__ __launch_bounds__(64) void bounds_kernel(const float* __restrict__ Llast,
                                                    float* __restrict__ bounds) {
    const int s = blockIdx.x;
    const int lane = threadIdx.x;
    const int c0 = lane * 8;
    float jc[8];
#pragma unroll
    for (int i = 0; i < 8; ++i) jc[i] = A_W * (float)(c0 + i);
    const float* Lb = Llast + (size_t)s * NSTRIP * WDIM;
    float* Bb = bounds + (size_t)s * NSTRIP * WDIM;

    float b[8];
    {
        float4 l0 = *(const float4*)(Lb + c0);
        float4 l1 = *(const float4*)(Lb + c0 + 4);
        b[0]=l0.x; b[1]=l0.y; b[2]=l0.z; b[3]=l0.w;
        b[4]=l1.x; b[5]=l1.y; b[6]=l1.z; b[7]=l1.w;
        *(float4*)(Bb + c0)     = l0;
        *(float4*)(Bb + c0 + 4) = l1;
    }
    for (int sig = 1; sig < NSTRIP; ++sig) {
        const float* Lr = Lb + (size_t)sig * WDIM + c0;
        float4 l0 = *(const float4*)Lr;
        float4 l1 = *(const float4*)(Lr + 4);
        t3x4(b); t3x4(b); t3x4(b); t3x4(b);      // T3^16 exact (TST==16)
        cummin_row(jc, b);
        b[0]=fminf(b[0],l0.x); b[1]=fminf(b[1],l0.y); b[2]=fminf(b[2],l0.z); b[3]=fminf(b[3],l0.w);
        b[4]=fminf(b[4],l1.x); b[5]=fminf(b[5],l1.y); b[6]=fminf(b[6],l1.z); b[7]=fminf(b[7],l1.w);
        float* Br = Bb + (size_t)sig * WDIM + c0;
        *(float4*)Br       = make_float4(b[0], b[1], b[2], b[3]);
        *(float4*)(Br + 4) = make_float4(b[4], b[5], b[6], b[7]);
    }
}

// Phase 3, pass 1: exact rows from exact incoming boundary; inline seeds; write all rows.
__global__ __launch_bounds__(64) void strip3a_kernel(const int* __restrict__ tg,
                                                     const int* __restrict__ flags,
                                                     const float* __restrict__ bounds,
                                                     float* __restrict__ dB) {
    const int s = blockIdx.x >> 5, sig = blockIdx.x & 31;
    const int lane = threadIdx.x;
    const int c0 = lane * 8;
    const int* tgb = tg + (size_t)s * NPIX;
    const bool useb = flags[s] != 0;
    const int R0 = sig * TST;
    float jc[8];
#pragma unroll
    for (int i = 0; i < 8; ++i) jc[i] = A_W * (float)(c0 + i);

    auto loadrow = [&](int rr) -> RowBits {
        if (rr < 0 || rr >= HDIM) { RowBits z; z.efg = 0; z.ebg = 0; z.rawbg = 0; return z; }
        const uint4* p = (const uint4*)(tgb + (size_t)rr * WDIM + c0);
        return make_rowbits(p[0], p[1]);
    };

    RowBits rA = loadrow(R0 - 1);
    RowBits rB = loadrow(R0);
    float prev[8];
    if (sig == 0) {
#pragma unroll
        for (int i = 0; i < 8; ++i) prev[i] = INF_W;
    } else {
        const float* Br = bounds + ((size_t)s * NSTRIP + (sig - 1)) * WDIM + c0;
        float4 b0 = *(const float4*)Br;
        float4 b1 = *(const float4*)(Br + 4);
        prev[0]=b0.x; prev[1]=b0.y; prev[2]=b0.z; prev[3]=b0.w;
        prev[4]=b1.x; prev[5]=b1.y; prev[6]=b1.z; prev[7]=b1.w;
    }
    float* dst = dB + (size_t)s * NPIX + (size_t)R0 * WDIM;
#pragma unroll
    for (int t = 0; t < TST; ++t) {
        RowBits rC = loadrow(R0 + t + 1);
        int smask = useb ? ((rA.efg | rB.efg | rC.efg) & (rA.ebg | rB.ebg | rC.ebg))
                         : rB.rawbg;
        float dr[8];
#pragma unroll
        for (int i = 0; i < 8; ++i) dr[i] = ((smask >> i) & 1) ? 0.f : INF_W;
        row_step(jc, prev, dr);
        float* p = dst + (size_t)t * WDIM + c0;
        *(float4*)p       = make_float4(prev[0], prev[1], prev[2], prev[3]);
        *(float4*)(p + 4) = make_float4(prev[4], prev[5], prev[6], prev[7]);
        rA = rB; rB = rC;
    }
}

// Phase 1, pass 2 (flipped): local strip scan over dB; write last row.
__global__ __launch_bounds__(64) void strip1b_kernel(const float* __restrict__ dB,
                                                     float* __restrict__ Llast) {
    const int s = blockIdx.x >> 5, sig = blockIdx.x & 31;
    const int lane = threadIdx.x;
    const int c0 = lane * 8;
    const size_t sb = (size_t)s * NPIX;
    float jc[8];
#pragma unroll
    for (int i = 0; i < 8; ++i) jc[i] = A_W * (float)(c0 + i);
    float prev[8];
#pragma unroll
    for (int i = 0; i < 8; ++i) prev[i] = INF_W;

#pragma unroll
    for (int t = 0; t < TST; ++t) {
        int pr = HDIM - 1 - (sig * TST + t);
        const float* p = dB + sb + (size_t)pr * WDIM + (WDIM - 8 - c0);
        float4 a = *(const float4*)p;
        float4 b = *(const float4*)(p + 4);
        float dr[8];
        dr[7]=a.x; dr[6]=a.y; dr[5]=a.z; dr[4]=a.w;
        dr[3]=b.x; dr[2]=b.y; dr[1]=b.z; dr[0]=b.w;
        row_step(jc, prev, dr);
    }
    float* Lr = Llast + ((size_t)s * NSTRIP + sig) * WDIM + c0;
    *(float4*)Lr       = make_float4(prev[0], prev[1], prev[2], prev[3]);
    *(float4*)(Lr + 4) = make_float4(prev[4], prev[5], prev[6], prev[7]);
}

// Phase 3, pass 2 (flipped) + FUSED loss: final DT never materialized.
__global__ __launch_bounds__(64) void strip3b_kernel(const float* __restrict__ dB,
                                                     const float* __restrict__ bounds,
                                                     const float* __restrict__ pred,
                                                     const int* __restrict__ tg,
                                                     float* __restrict__ stripacc) {
    const int s = blockIdx.x >> 5, sig = blockIdx.x & 31;
    const int lane = threadIdx.x;
    const int c0 = lane * 8;
    const size_t sb = (size_t)s * NPIX;
    float jc[8];
#pragma unroll
    for (int i = 0; i < 8; ++i) jc[i] = A_W * (float)(c0 + i);
    float prev[8];
    if (sig == 0) {
#pragma unroll
        for (int i = 0; i < 8; ++i) prev[i] = INF_W;
    } else {
        const float* Br = bounds + ((size_t)s * NSTRIP + (sig - 1)) * WDIM + c0;
        float4 b0 = *(const float4*)Br;
        float4 b1 = *(const float4*)(Br + 4);
        prev[0]=b0.x; prev[1]=b0.y; prev[2]=b0.z; prev[3]=b0.w;
        prev[4]=b1.x; prev[5]=b1.y; prev[6]=b1.z; prev[7]=b1.w;
    }
    float mx = 0.f, facc = 0.f, s1 = 0.f, s2 = 0.f, iacc = 0.f, pacc = 0.f;
#pragma unroll
    for (int t = 0; t < TST; ++t) {
        int pr = HDIM - 1 - (sig * TST + t);
        const size_t rbase = sb + (size_t)pr * WDIM + (WDIM - 8 - c0);
        const float* p = dB + rbase;
        float4 a = *(const float4*)p;
        float4 b = *(const float4*)(p + 4);
        float dr[8];
        dr[7]=a.x; dr[6]=a.y; dr[5]=a.z; dr[4]=a.w;
        dr[3]=b.x; dr[2]=b.y; dr[1]=b.z; dr[0]=b.w;
        float4 xa = *(const float4*)(pred + rbase);
        float4 xb = *(const float4*)(pred + rbase + 4);
        float px[8];
        px[7]=xa.x; px[6]=xa.y; px[5]=xa.z; px[4]=xa.w;
        px[3]=xb.x; px[2]=xb.y; px[1]=xb.z; px[0]=xb.w;
        int4 ta = *(const int4*)(tg + rbase);
        int4 tb = *(const int4*)(tg + rbase + 4);
        int ti[8];
        ti[7]=ta.x; ti[6]=ta.y; ti[5]=ta.z; ti[4]=ta.w;
        ti[3]=tb.x; ti[2]=tb.y; ti[1]=tb.z; ti[0]=tb.w;

        row_step(jc, prev, dr);
#pragma unroll
        for (int i = 0; i < 8; ++i) {
            float x = px[i];
            float dd = prev[i];
            float e = __expf(-fabsf(x));
            float inv = 1.f / (1.f + e);
            float pr_ = (x >= 0.f) ? inv : (1.f - inv);   // sigmoid(x)
            float L = __logf(1.f + e);                    // softplus(-|x|)
            bool t1 = ti[i] != 0;
            float fo = t1 ? 0.25f * (1.f - pr_) * (1.f - pr_) * (fmaxf(-x, 0.f) + L)
                          : 0.75f * pr_ * pr_ * (fmaxf(x, 0.f) + L);
            facc += fo;
            float base = t1 ? (1.f - pr_) : pr_;
            s1 += base;
            s2 += base * dd;
            float tf = t1 ? 1.f : 0.f;
            iacc += tf * pr_;
            pacc += pr_ + tf;
            mx = fmaxf(mx, dd);
        }
    }
#pragma unroll
    for (int off = 32; off > 0; off >>= 1) {
        facc += __shfl_xor(facc, off);
        s1   += __shfl_xor(s1, off);
        s2   += __shfl_xor(s2, off);
        iacc += __shfl_xor(iacc, off);
        pacc += __shfl_xor(pacc, off);
        mx    = fmaxf(mx, __shfl_xor(mx, off));
    }
    if (lane == 0) {
        const int idx = s * NSTRIP + sig;
        stripacc[0 * 512 + idx] = s1;
        stripacc[1 * 512 + idx] = s2;
        stripacc[2 * 512 + idx] = iacc;
        stripacc[3 * 512 + idx] = pacc;
        stripacc[4 * 512 + idx] = mx;
        stripacc[5 * 512 + idx] = facc;
    }
}

__global__ __launch_bounds__(64) void sampred_kernel(const float* __restrict__ stripacc,
                                                     float* __restrict__ acc) {
    const int s = blockIdx.x;
    const int lane = threadIdx.x;
    const bool v = lane < NSTRIP;
    const int idx = s * NSTRIP + (lane & 31);
    float s1   = v ? stripacc[0 * 512 + idx] : 0.f;
    float s2   = v ? stripacc[1 * 512 + idx] : 0.f;
    float iacc = v ? stripacc[2 * 512 + idx] : 0.f;
    float pacc = v ? stripacc[3 * 512 + idx] : 0.f;
    float mx   = v ? stripacc[4 * 512 + idx] : 0.f;
    float facc = v ? stripacc[5 * 512 + idx] : 0.f;
#pragma unroll
    for (int off = 32; off > 0; off >>= 1) {
        s1   += __shfl_xor(s1, off);
        s2   += __shfl_xor(s2, off);
        iacc += __shfl_xor(iacc, off);
        pacc += __shfl_xor(pacc, off);
        facc += __shfl_xor(facc, off);
        mx    = fmaxf(mx, __shfl_xor(mx, off));
    }
    if (lane == 0) {
        acc[s]      = s1;
        acc[16 + s] = s2;
        acc[32 + s] = iacc;
        acc[48 + s] = pacc;
        acc[64 + s] = mx;
        acc[80 + s] = facc;
    }
}

__global__ void final_kernel(const float* __restrict__ acc, const int* __restrict__ flags,
                             const float* __restrict__ lv, float* __restrict__ out) {
    if (threadIdx.x == 0) {
        float fsum = 0.f, bsum = 0.f, dsum = 0.f, isum = 0.f;
        for (int s = 0; s < NSAMP; ++s) {
            fsum += acc[80 + s];
            float S1 = acc[s], S2 = acc[16 + s], mxs = acc[64 + s];
            bool hfg = flags[16 + s] != 0;
            float distsum = hfg ? ((mxs > 0.f) ? S2 / fmaxf(mxs, 1e-12f) : 0.f) : S1;
            bsum += S1 + distsum;
            float inter = acc[32 + s];
            float tot   = acc[48 + s];
            dsum += (2.f * inter + 1e-6f) / (tot + 1e-6f);
            isum += (inter + 1e-6f) / (tot - inter + 1e-6f);
        }
        float focal = fsum / NTOT_F;
        float bnd   = bsum / NTOT_F;
        float dice = 1.f - dsum / 16.f;
        float iou  = 1.f - isum / 16.f;
        float l0 = lv[0], l1 = lv[1], l2 = lv[2], l3 = lv[3];
        float total = expf(-l0) * focal + l0 + expf(-l1) * dice + l1
                    + expf(-l2) * bnd  + l2 + expf(-l3) * iou  + l3;
        out[0] = total; out[1] = focal; out[2] = dice; out[3] = bnd; out[4] = iou;
    }
}

extern "C" void kernel_launch(void* const* d_in, const int* in_sizes, int n_in,
                              void* d_out, int out_size, void* d_ws, size_t ws_size,
                              hipStream_t stream) {
    const float* pred = (const float*)d_in[0];
    const int*   tg   = (const int*)d_in[1];
    const float* lv   = (const float*)d_in[2];
    float* out = (float*)d_out;
    char* ws = (char*)d_ws;
    float* acc      = (float*)ws;
    int*   flags    = (int*)(ws + 512);
    int*   blkflags = (int*)(ws + 1024);
    float* sacc     = (float*)(ws + OFF_SACC);
    float* Llast    = (float*)(ws + OFF_LLAST);
    float* bounds   = (float*)(ws + OFF_BOUNDS);
    float* dB       = (float*)(ws + OFF_DB);

    flags1_kernel<<<256, 256, 0, stream>>>(tg, blkflags);
    flags2_kernel<<<NSAMP, 64, 0, stream>>>(blkflags, flags);
    // pass 1 (top-down), seeds computed inline
    strip1a_kernel<<<NSAMP * NSTRIP, 64, 0, stream>>>(tg, flags, Llast);
    bounds_kernel<<<NSAMP, 64, 0, stream>>>(Llast, bounds);
    strip3a_kernel<<<NSAMP * NSTRIP, 64, 0, stream>>>(tg, flags, bounds, dB);
    // pass 2 (bottom-up, flipped), loss fused into phase 3
    strip1b_kernel<<<NSAMP * NSTRIP, 64, 0, stream>>>(dB, Llast);
    bounds_kernel<<<NSAMP, 64, 0, stream>>>(Llast, bounds);
    strip3b_kernel<<<NSAMP * NSTRIP, 64, 0, stream>>>(dB, bounds, pred, tg, sacc);
    sampred_kernel<<<NSAMP, 64, 0, stream>>>(sacc, acc);
    final_kernel<<<1, 64, 0, stream>>>(acc, flags, lv, out);
}

// Round 10
// 201.101 us; speedup vs baseline: 2.3433x; 2.3433x over previous
//
#include <hip/hip_runtime.h>
#include <math.h>

#define A_W 0.955f
#define B_W 1.3693f
#define INF_W 1e6f
#define HDIM 512
#define WDIM 512
#define NPIX (HDIM*WDIM)
#define NSAMP 16
#define NTOT_F 4194304.0f
#define TST 16      // strip height
#define NSTRIP 32   // strips per sample

// ws layout (bytes):
//  [0,384):        float acc[96]: [s]=S1 [16+s]=S2 [32+s]=inter [48+s]=totp [64+s]=mx [80+s]=focal
//  [512,768):      int flags[64]: [0..15]=has_b [16..31]=has_fg
//  [1024,5120):    int blkflags[1024]
//  [8192,20480):   float stripacc[6][512]
//  [1MB,2MB):      float Llast[16][32][512]
//  [2MB,3MB):      float bounds[16][32][512]
//  [3MB,19MB):     float dB[16][512][512]   (pass-1 result)
#define OFF_SACC   8192
#define OFF_LLAST  (1u<<20)
#define OFF_BOUNDS (2u<<20)
#define OFF_DB     (3u<<20)

// DPP move with INF fill (floats).
//   WAVE_SHR1 (0x138): lane i <- lane i-1 (== __shfl_up 1)
//   WAVE_SHL1 (0x130): lane i <- lane i+1 (== __shfl_down 1)
template<int CTRL, int RMASK>
__device__ __forceinline__ float dpp_mov_inf(float x) {
    return __int_as_float(__builtin_amdgcn_update_dpp(
        __float_as_int(INF_W), __float_as_int(x), CTRL, RMASK, 0xF, false));
}
// DPP move with 0 fill (ints; bound_ctrl=1 -> OOB lanes read 0).
template<int CTRL>
__device__ __forceinline__ int dpp_mov0_i(int x) {
    return __builtin_amdgcn_update_dpp(0, x, CTRL, 0xF, 0xF, true);
}

__device__ __forceinline__ float wave_prefix_min_incl(float t) {
    t = fminf(t, dpp_mov_inf<0x111,0xF>(t));   // row_shr:1
    t = fminf(t, dpp_mov_inf<0x112,0xF>(t));   // row_shr:2
    t = fminf(t, dpp_mov_inf<0x114,0xF>(t));   // row_shr:4
    t = fminf(t, dpp_mov_inf<0x118,0xF>(t));   // row_shr:8
    t = fminf(t, dpp_mov_inf<0x142,0xA>(t));   // row_bcast:15 -> rows 1,3
    t = fminf(t, dpp_mov_inf<0x143,0xC>(t));   // row_bcast:31 -> rows 2,3
    return t;
}

// v[j] <- min_{k<=j} (v[k] + A*(j-k))
__device__ __forceinline__ void cummin_row(const float* jc, float* v) {
    float g[8];
#pragma unroll
    for (int i = 0; i < 8; ++i) g[i] = v[i] - jc[i];
    float c1[8];
    c1[0] = g[0];
#pragma unroll
    for (int i = 1; i < 8; ++i) c1[i] = fminf(g[i], g[i-1]);
    float c2[8];
    c2[0] = c1[0]; c2[1] = c1[1];
#pragma unroll
    for (int i = 2; i < 8; ++i) c2[i] = fminf(c1[i], c1[i-2]);
    float cj[8];
    cj[0] = c2[0]; cj[1] = c2[1]; cj[2] = c2[2]; cj[3] = c2[3];
#pragma unroll
    for (int i = 4; i < 8; ++i) cj[i] = fminf(c2[i], c2[i-4]);
    float t  = wave_prefix_min_incl(cj[7]);
    float ex = dpp_mov_inf<0x138,0xF>(t);
#pragma unroll
    for (int i = 0; i < 8; ++i) v[i] = jc[i] + fminf(cj[i], ex);
}

__device__ __forceinline__ void row_step(const float* jc, float* prev, const float* drow) {
    float lIn = dpp_mov_inf<0x138,0xF>(prev[7]);
    float rIn = dpp_mov_inf<0x130,0xF>(prev[0]);
    float m[8];
#pragma unroll
    for (int i = 0; i < 8; ++i) {
        float up = prev[i] + A_W;
        float ul = ((i == 0) ? lIn : prev[i-1]) + B_W;
        float ur = ((i == 7) ? rIn : prev[i+1]) + B_W;
        m[i] = fminf(fminf(drow[i], up), fminf(ul, ur));
    }
    cummin_row(jc, m);
#pragma unroll
    for (int i = 0; i < 8; ++i) prev[i] = m[i];
}

// 4 fused T3 steps (exact, INF outside grid).
__device__ __forceinline__ void t3x4(float* b) {
    float e[16];
#pragma unroll
    for (int k = 0; k < 4; ++k) e[k]    = dpp_mov_inf<0x138,0xF>(b[4+k]);
#pragma unroll
    for (int k = 0; k < 8; ++k) e[4+k]  = b[k];
#pragma unroll
    for (int k = 0; k < 4; ++k) e[12+k] = dpp_mov_inf<0x130,0xF>(b[k]);
    const float w0 = 4.f*A_W, w1 = 3.f*A_W + B_W, w2 = 2.f*A_W + 2.f*B_W;
    const float w3 = A_W + 3.f*B_W, w4 = 4.f*B_W;
#pragma unroll
    for (int i = 0; i < 8; ++i) {
        float m = e[i+4] + w0;
        m = fminf(m, fminf(e[i+3], e[i+5]) + w1);
        m = fminf(m, fminf(e[i+2], e[i+6]) + w2);
        m = fminf(m, fminf(e[i+1], e[i+7]) + w3);
        m = fminf(m, fminf(e[i+0], e[i+8]) + w4);
        b[i] = m;
    }
}

// ---- inline seed machinery --------------------------------------------------
struct RowBits { int efg; int ebg; int rawbg; };

__device__ __forceinline__ RowBits make_rowbits(uint4 a, uint4 b) {
    int fg = ((a.x!=0u)?1:0) | ((a.y!=0u)?2:0) | ((a.z!=0u)?4:0) | ((a.w!=0u)?8:0)
           | ((b.x!=0u)?16:0) | ((b.y!=0u)?32:0) | ((b.z!=0u)?64:0) | ((b.w!=0u)?128:0);
    int bg = (~fg) & 0xFF;
    int lf = dpp_mov0_i<0x138>(fg), rf = dpp_mov0_i<0x130>(fg);
    int lb = dpp_mov0_i<0x138>(bg), rb = dpp_mov0_i<0x130>(bg);
    RowBits r;
    r.efg = (fg | (fg<<1) | (fg>>1) | ((lf>>7)&1) | ((rf&1)<<7)) & 0xFF;
    r.ebg = (bg | (bg<<1) | (bg>>1) | ((lb>>7)&1) | ((rb&1)<<7)) & 0xFF;
    r.rawbg = bg;
    return r;
}

// ---- flags: has_fg / has_bg (has_b == has_fg && has_bg) ---------------------
__global__ __launch_bounds__(256) void flags1_kernel(const int* __restrict__ tg,
                                                     int* __restrict__ blkflags) {
    const int4* p = (const int4*)tg + (size_t)blockIdx.x * 4096 + threadIdx.x;
    int fgany = 0, bgany = 0;
#pragma unroll 4
    for (int i = 0; i < 16; ++i) {
        int4 v = p[i * 256];
        fgany |= (v.x | v.y | v.z | v.w);
        bgany |= (v.x == 0) | (v.y == 0) | (v.z == 0) | (v.w == 0);
    }
    int wf = __any(fgany != 0) ? 1 : 0;
    int wb = __any(bgany != 0) ? 2 : 0;
    if ((threadIdx.x & 63) == 0) blkflags[blockIdx.x * 4 + (threadIdx.x >> 6)] = wf | wb;
}

__global__ __launch_bounds__(64) void flags2_kernel(const int* __restrict__ blkflags,
                                                    int* __restrict__ flags) {
    const int s = blockIdx.x;
    const int lane = threadIdx.x;
    int v = blkflags[s * 64 + lane];
#pragma unroll
    for (int off = 32; off > 0; off >>= 1) v |= __shfl_xor(v, off);
    if (lane == 0) {
        int hfg = v & 1, hbg = (v >> 1) & 1;
        flags[s] = hfg & hbg;     // has_b
        flags[16 + s] = hfg;      // has_fg
    }
}

// Phase 1, pass 1: local strip scan with inline seeds; write last row only.
__global__ __launch_bounds__(64) void strip1a_kernel(const int* __restrict__ tg,
                                                     const int* __restrict__ flags,
                                                     float* __restrict__ Llast) {
    const int s = blockIdx.x >> 5, sig = blockIdx.x & 31;
    const int lane = threadIdx.x;
    const int c0 = lane * 8;
    const int* tgb = tg + (size_t)s * NPIX;
    const bool useb = flags[s] != 0;
    const int R0 = sig * TST;
    float jc[8];
#pragma unroll
    for (int i = 0; i < 8; ++i) jc[i] = A_W * (float)(c0 + i);

    auto loadrow = [&](int rr) -> RowBits {
        if (rr < 0 || rr >= HDIM) { RowBits z; z.efg = 0; z.ebg = 0; z.rawbg = 0; return z; }
        const uint4* p = (const uint4*)(tgb + (size_t)rr * WDIM + c0);
        return make_rowbits(p[0], p[1]);
    };

    RowBits rA = loadrow(R0 - 1);
    RowBits rB = loadrow(R0);
    float prev[8];
#pragma unroll
    for (int i = 0; i < 8; ++i) prev[i] = INF_W;

#pragma unroll
    for (int t = 0; t < TST; ++t) {
        RowBits rC = loadrow(R0 + t + 1);
        int smask = useb ? ((rA.efg | rB.efg | rC.efg) & (rA.ebg | rB.ebg | rC.ebg))
                         : rB.rawbg;
        float dr[8];
#pragma unroll
        for (int i = 0; i < 8; ++i) dr[i] = ((smask >> i) & 1) ? 0.f : INF_W;
        row_step(jc, prev, dr);
        rA = rB; rB = rC;
    }
    float* Lr = Llast + ((size_t)s * NSTRIP + sig) * WDIM + c0;
    *(float4*)Lr       = make_float4(prev[0], prev[1], prev[2], prev[3]);
    *(float4*)(Lr + 4) = make_float4(prev[4], prev[5], prev[6], prev[7]);
}

// Phase 2: exact sequential boundary propagation across strips.
__global__ __launch_bounds__(64) void bounds_kernel(const float* __restrict__ Llast,
                                                    float* __restrict__ bounds) {
    const int s = blockIdx.x;
    const int lane = threadIdx.x;
    const int c0 = lane * 8;
    float jc[8];
#pragma unroll
    for (int i = 0; i < 8; ++i) jc[i] = A_W * (float)(c0 + i);
    const float* Lb = Llast + (size_t)s * NSTRIP * WDIM;
    float* Bb = bounds + (size_t)s * NSTRIP * WDIM;

    float b[8];
    {
        float4 l0 = *(const float4*)(Lb + c0);
        float4 l1 = *(const float4*)(Lb + c0 + 4);
        b[0]=l0.x; b[1]=l0.y; b[2]=l0.z; b[3]=l0.w;
        b[4]=l1.x; b[5]=l1.y; b[6]=l1.z; b[7]=l1.w;
        *(float4*)(Bb + c0)     = l0;
        *(float4*)(Bb + c0 + 4) = l1;
    }
    for (int sig = 1; sig < NSTRIP; ++sig) {
        const float* Lr = Lb + (size_t)sig * WDIM + c0;
        float4 l0 = *(const float4*)Lr;
        float4 l1 = *(const float4*)(Lr + 4);
        t3x4(b); t3x4(b); t3x4(b); t3x4(b);      // T3^16 exact (TST==16)
        cummin_row(jc, b);
        b[0]=fminf(b[0],l0.x); b[1]=fminf(b[1],l0.y); b[2]=fminf(b[2],l0.z); b[3]=fminf(b[3],l0.w);
        b[4]=fminf(b[4],l1.x); b[5]=fminf(b[5],l1.y); b[6]=fminf(b[6],l1.z); b[7]=fminf(b[7],l1.w);
        float* Br = Bb + (size_t)sig * WDIM + c0;
        *(float4*)Br       = make_float4(b[0], b[1], b[2], b[3]);
        *(float4*)(Br + 4) = make_float4(b[4], b[5], b[6], b[7]);
    }
}

// Phase 3, pass 1: exact rows from exact incoming boundary; inline seeds; write all rows.
__global__ __launch_bounds__(64) void strip3a_kernel(const int* __restrict__ tg,
                                                     const int* __restrict__ flags,
                                                     const float* __restrict__ bounds,
                                                     float* __restrict__ dB) {
    const int s = blockIdx.x >> 5, sig = blockIdx.x & 31;
    const int lane = threadIdx.x;
    const int c0 = lane * 8;
    const int* tgb = tg + (size_t)s * NPIX;
    const bool useb = flags[s] != 0;
    const int R0 = sig * TST;
    float jc[8];
#pragma unroll
    for (int i = 0; i < 8; ++i) jc[i] = A_W * (float)(c0 + i);

    auto loadrow = [&](int rr) -> RowBits {
        if (rr < 0 || rr >= HDIM) { RowBits z; z.efg = 0; z.ebg = 0; z.rawbg = 0; return z; }
        const uint4* p = (const uint4*)(tgb + (size_t)rr * WDIM + c0);
        return make_rowbits(p[0], p[1]);
    };

    RowBits rA = loadrow(R0 - 1);
    RowBits rB = loadrow(R0);
    float prev[8];
    if (sig == 0) {
#pragma unroll
        for (int i = 0; i < 8; ++i) prev[i] = INF_W;
    } else {
        const float* Br = bounds + ((size_t)s * NSTRIP + (sig - 1)) * WDIM + c0;
        float4 b0 = *(const float4*)Br;
        float4 b1 = *(const float4*)(Br + 4);
        prev[0]=b0.x; prev[1]=b0.y; prev[2]=b0.z; prev[3]=b0.w;
        prev[4]=b1.x; prev[5]=b1.y; prev[6]=b1.z; prev[7]=b1.w;
    }
    float* dst = dB + (size_t)s * NPIX + (size_t)R0 * WDIM;
#pragma unroll
    for (int t = 0; t < TST; ++t) {
        RowBits rC = loadrow(R0 + t + 1);
        int smask = useb ? ((rA.efg | rB.efg | rC.efg) & (rA.ebg | rB.ebg | rC.ebg))
                         : rB.rawbg;
        float dr[8];
#pragma unroll
        for (int i = 0; i < 8; ++i) dr[i] = ((smask >> i) & 1) ? 0.f : INF_W;
        row_step(jc, prev, dr);
        float* p = dst + (size_t)t * WDIM + c0;
        *(float4*)p       = make_float4(prev[0], prev[1], prev[2], prev[3]);
        *(float4*)(p + 4) = make_float4(prev[4], prev[5], prev[6], prev[7]);
        rA = rB; rB = rC;
    }
}

// Phase 1, pass 2 (flipped): local strip scan over dB; write last row.
__global__ __launch_bounds__(64) void strip1b_kernel(const float* __restrict__ dB,
                                                     float* __restrict__ Llast) {
    const int s = blockIdx.x >> 5, sig = blockIdx.x & 31;
    const int lane = threadIdx.x;
    const int c0 = lane * 8;
    const size_t sb = (size_t)s * NPIX;
    float jc[8];
#pragma unroll
    for (int i = 0; i < 8; ++i) jc[i] = A_W * (float)(c0 + i);
    float prev[8];
#pragma unroll
    for (int i = 0; i < 8; ++i) prev[i] = INF_W;

#pragma unroll
    for (int t = 0; t < TST; ++t) {
        int pr = HDIM - 1 - (sig * TST + t);
        const float* p = dB + sb + (size_t)pr * WDIM + (WDIM - 8 - c0);
        float4 a = *(const float4*)p;
        float4 b = *(const float4*)(p + 4);
        float dr[8];
        dr[7]=a.x; dr[6]=a.y; dr[5]=a.z; dr[4]=a.w;
        dr[3]=b.x; dr[2]=b.y; dr[1]=b.z; dr[0]=b.w;
        row_step(jc, prev, dr);
    }
    float* Lr = Llast + ((size_t)s * NSTRIP + sig) * WDIM + c0;
    *(float4*)Lr       = make_float4(prev[0], prev[1], prev[2], prev[3]);
    *(float4*)(Lr + 4) = make_float4(prev[4], prev[5], prev[6], prev[7]);
}

// Phase 3, pass 2 (flipped) + FUSED loss. #pragma unroll 2 caps register pressure:
// round-9's full unroll hoisted 96 float4 loads -> VGPR=256 + 51MB scratch spill.
__global__ __launch_bounds__(64) void strip3b_kernel(const float* __restrict__ dB,
                                                     const float* __restrict__ bounds,
                                                     const float* __restrict__ pred,
                                                     const int* __restrict__ tg,
                                                     float* __restrict__ stripacc) {
    const int s = blockIdx.x >> 5, sig = blockIdx.x & 31;
    const int lane = threadIdx.x;
    const int c0 = lane * 8;
    const size_t sb = (size_t)s * NPIX;
    float jc[8];
#pragma unroll
    for (int i = 0; i < 8; ++i) jc[i] = A_W * (float)(c0 + i);
    float prev[8];
    if (sig == 0) {
#pragma unroll
        for (int i = 0; i < 8; ++i) prev[i] = INF_W;
    } else {
        const float* Br = bounds + ((size_t)s * NSTRIP + (sig - 1)) * WDIM + c0;
        float4 b0 = *(const float4*)Br;
        float4 b1 = *(const float4*)(Br + 4);
        prev[0]=b0.x; prev[1]=b0.y; prev[2]=b0.z; prev[3]=b0.w;
        prev[4]=b1.x; prev[5]=b1.y; prev[6]=b1.z; prev[7]=b1.w;
    }
    float mx = 0.f, facc = 0.f, s1 = 0.f, s2 = 0.f, iacc = 0.f, pacc = 0.f;
#pragma unroll 2
    for (int t = 0; t < TST; ++t) {
        int pr = HDIM - 1 - (sig * TST + t);
        const size_t rbase = sb + (size_t)pr * WDIM + (WDIM - 8 - c0);
        const float* p = dB + rbase;
        float4 a = *(const float4*)p;
        float4 b = *(const float4*)(p + 4);
        float dr[8];
        dr[7]=a.x; dr[6]=a.y; dr[5]=a.z; dr[4]=a.w;
        dr[3]=b.x; dr[2]=b.y; dr[1]=b.z; dr[0]=b.w;
        float4 xa = *(const float4*)(pred + rbase);
        float4 xb = *(const float4*)(pred + rbase + 4);
        float px[8];
        px[7]=xa.x; px[6]=xa.y; px[5]=xa.z; px[4]=xa.w;
        px[3]=xb.x; px[2]=xb.y; px[1]=xb.z; px[0]=xb.w;
        int4 ta = *(const int4*)(tg + rbase);
        int4 tb = *(const int4*)(tg + rbase + 4);
        int ti[8];
        ti[7]=ta.x; ti[6]=ta.y; ti[5]=ta.z; ti[4]=ta.w;
        ti[3]=tb.x; ti[2]=tb.y; ti[1]=tb.z; ti[0]=tb.w;

        row_step(jc, prev, dr);
#pragma unroll
        for (int i = 0; i < 8; ++i) {
            float x = px[i];
            float dd = prev[i];
            float e = __expf(-fabsf(x));
            float inv = 1.f / (1.f + e);
            float pr_ = (x >= 0.f) ? inv : (1.f - inv);   // sigmoid(x)
            float L = __logf(1.f + e);                    // softplus(-|x|)
            bool t1 = ti[i] != 0;
            float fo = t1 ? 0.25f * (1.f - pr_) * (1.f - pr_) * (fmaxf(-x, 0.f) + L)
                          : 0.75f * pr_ * pr_ * (fmaxf(x, 0.f) + L);
            facc += fo;
            float base = t1 ? (1.f - pr_) : pr_;
            s1 += base;
            s2 += base * dd;
            float tf = t1 ? 1.f : 0.f;
            iacc += tf * pr_;
            pacc += pr_ + tf;
            mx = fmaxf(mx, dd);
        }
    }
#pragma unroll
    for (int off = 32; off > 0; off >>= 1) {
        facc += __shfl_xor(facc, off);
        s1   += __shfl_xor(s1, off);
        s2   += __shfl_xor(s2, off);
        iacc += __shfl_xor(iacc, off);
        pacc += __shfl_xor(pacc, off);
        mx    = fmaxf(mx, __shfl_xor(mx, off));
    }
    if (lane == 0) {
        const int idx = s * NSTRIP + sig;
        stripacc[0 * 512 + idx] = s1;
        stripacc[1 * 512 + idx] = s2;
        stripacc[2 * 512 + idx] = iacc;
        stripacc[3 * 512 + idx] = pacc;
        stripacc[4 * 512 + idx] = mx;
        stripacc[5 * 512 + idx] = facc;
    }
}

__global__ __launch_bounds__(64) void sampred_kernel(const float* __restrict__ stripacc,
                                                     float* __restrict__ acc) {
    const int s = blockIdx.x;
    const int lane = threadIdx.x;
    const bool v = lane < NSTRIP;
    const int idx = s * NSTRIP + (lane & 31);
    float s1   = v ? stripacc[0 * 512 + idx] : 0.f;
    float s2   = v ? stripacc[1 * 512 + idx] : 0.f;
    float iacc = v ? stripacc[2 * 512 + idx] : 0.f;
    float pacc = v ? stripacc[3 * 512 + idx] : 0.f;
    float mx   = v ? stripacc[4 * 512 + idx] : 0.f;
    float facc = v ? stripacc[5 * 512 + idx] : 0.f;
#pragma unroll
    for (int off = 32; off > 0; off >>= 1) {
        s1   += __shfl_xor(s1, off);
        s2   += __shfl_xor(s2, off);
        iacc += __shfl_xor(iacc, off);
        pacc += __shfl_xor(pacc, off);
        facc += __shfl_xor(facc, off);
        mx    = fmaxf(mx, __shfl_xor(mx, off));
    }
    if (lane == 0) {
        acc[s]      = s1;
        acc[16 + s] = s2;
        acc[32 + s] = iacc;
        acc[48 + s] = pacc;
        acc[64 + s] = mx;
        acc[80 + s] = facc;
    }
}

__global__ void final_kernel(const float* __restrict__ acc, const int* __restrict__ flags,
                             const float* __restrict__ lv, float* __restrict__ out) {
    if (threadIdx.x == 0) {
        float fsum = 0.f, bsum = 0.f, dsum = 0.f, isum = 0.f;
        for (int s = 0; s < NSAMP; ++s) {
            fsum += acc[80 + s];
            float S1 = acc[s], S2 = acc[16 + s], mxs = acc[64 + s];
            bool hfg = flags[16 + s] != 0;
            float distsum = hfg ? ((mxs > 0.f) ? S2 / fmaxf(mxs, 1e-12f) : 0.f) : S1;
            bsum += S1 + distsum;
            float inter = acc[32 + s];
            float tot   = acc[48 + s];
            dsum += (2.f * inter + 1e-6f) / (tot + 1e-6f);
            isum += (inter + 1e-6f) / (tot - inter + 1e-6f);
        }
        float focal = fsum / NTOT_F;
        float bnd   = bsum / NTOT_F;
        float dice = 1.f - dsum / 16.f;
        float iou  = 1.f - isum / 16.f;
        float l0 = lv[0], l1 = lv[1], l2 = lv[2], l3 = lv[3];
        float total = expf(-l0) * focal + l0 + expf(-l1) * dice + l1
                    + expf(-l2) * bnd  + l2 + expf(-l3) * iou  + l3;
        out[0] = total; out[1] = focal; out[2] = dice; out[3] = bnd; out[4] = iou;
    }
}

extern "C" void kernel_launch(void* const* d_in, const int* in_sizes, int n_in,
                              void* d_out, int out_size, void* d_ws, size_t ws_size,
                              hipStream_t stream) {
    const float* pred = (const float*)d_in[0];
    const int*   tg   = (const int*)d_in[1];
    const float* lv   = (const float*)d_in[2];
    float* out = (float*)d_out;
    char* ws = (char*)d_ws;
    float* acc      = (float*)ws;
    int*   flags    = (int*)(ws + 512);
    int*   blkflags = (int*)(ws + 1024);
    float* sacc     = (float*)(ws + OFF_SACC);
    float* Llast    = (float*)(ws + OFF_LLAST);
    float* bounds   = (float*)(ws + OFF_BOUNDS);
    float* dB       = (float*)(ws + OFF_DB);

    flags1_kernel<<<256, 256, 0, stream>>>(tg, blkflags);
    flags2_kernel<<<NSAMP, 64, 0, stream>>>(blkflags, flags);
    // pass 1 (top-down), seeds computed inline
    strip1a_kernel<<<NSAMP * NSTRIP, 64, 0, stream>>>(tg, flags, Llast);
    bounds_kernel<<<NSAMP, 64, 0, stream>>>(Llast, bounds);
    strip3a_kernel<<<NSAMP * NSTRIP, 64, 0, stream>>>(tg, flags, bounds, dB);
    // pass 2 (bottom-up, flipped), loss fused into phase 3
    strip1b_kernel<<<NSAMP * NSTRIP, 64, 0, stream>>>(dB, Llast);
    bounds_kernel<<<NSAMP, 64, 0, stream>>>(Llast, bounds);
    strip3b_kernel<<<NSAMP * NSTRIP, 64, 0, stream>>>(dB, bounds, pred, tg, sacc);
    sampred_kernel<<<NSAMP, 64, 0, stream>>>(sacc, acc);
    final_kernel<<<1, 64, 0, stream>>>(acc, flags, lv, out);
}